// Round 5
// baseline (129.369 us; speedup 1.0000x reference)
//
#include <hip/hip_runtime.h>
#include <math.h>

#define B_ROWS 4096
#define T_COLS 4096
#define NTHREADS 256
#define WPB (NTHREADS / 64)       // 4 waves per block, one ROW per WAVE
#define NBLOCKS (B_ROWS / WPB)    // 1024 blocks = 4/CU = 16 waves/CU

// Force a (wave-uniform) float into an SGPR.
__device__ __forceinline__ float rfl(float v) {
    return __int_as_float(__builtin_amdgcn_readfirstlane(__float_as_int(v)));
}

#define STEP(z, xv) fmaf(beta, (z), fmaf(alpha, (xv) * (xv), omega))
#define SQ(z) __builtin_amdgcn_sqrtf(z)

__global__ __launch_bounds__(NTHREADS, 4) void garch_fused(
    const float* __restrict__ x,
    const float* __restrict__ p_omega_log,
    const float* __restrict__ p_alpha_log,
    const float* __restrict__ p_beta_log,
    float* __restrict__ out)
{
    const int lane = threadIdx.x & 63;
    const int wv   = threadIdx.x >> 6;
    const long row = (long)blockIdx.x * WPB + wv;

    // ---- Strided loads: lane owns elements [64*lane, 64*lane+64) of its row.
    // 16 independent dwordx4 in flight per wave; each 64B line fetched once.
    const float4* xr4 = reinterpret_cast<const float4*>(x + row * T_COLS) + lane * 16;
    float xs[64];
#pragma unroll
    for (int j = 0; j < 16; ++j)
        *reinterpret_cast<float4*>(&xs[4 * j]) = xr4[j];

    // ---- Uniform scalar parameter work -> SGPRs (overlaps the loads) ----
    float ea_p  = expf(p_alpha_log[0]);
    float eb_p  = expf(p_beta_log[0]);
    float denom = 1.0f + ea_p + eb_p;
    float omega = rfl(expf(p_omega_log[0]));
    float alpha = rfl(ea_p / denom);
    float beta  = rfl(eb_p / denom);
    float beta2  = beta * beta;
    float beta4  = beta2 * beta2;
    float beta8  = beta4 * beta4;
    float beta16 = beta8 * beta8;
    float beta32 = beta16 * beta16;
    float beta31 = beta16 * beta8 * beta4 * beta2 * beta;

    // ---- Per-lane sum/ssq over 64 elements (4 accumulators for ILP) ----
    float a0 = 0, a1 = 0, a2 = 0, a3 = 0, q0 = 0, q1 = 0, q2 = 0, q3 = 0;
#pragma unroll
    for (int k = 0; k < 64; k += 4) {
        a0 += xs[k + 0]; q0 = fmaf(xs[k + 0], xs[k + 0], q0);
        a1 += xs[k + 1]; q1 = fmaf(xs[k + 1], xs[k + 1], q1);
        a2 += xs[k + 2]; q2 = fmaf(xs[k + 2], xs[k + 2], q2);
        a3 += xs[k + 3]; q3 = fmaf(xs[k + 3], xs[k + 3], q3);
    }
    float s1 = (a0 + a1) + (a2 + a3);
    float s2 = (q0 + q1) + (q2 + q3);

    // prev = x[64*lane - 1]: lane-1's last element (unused by lane 0).
    float prev = __shfl_up(xs[63], 1);

    // ---- Zero-init affine map of this lane's 64-step segment, in two
    // independent 32-step halves (2x ILP on the serial fma chain).
    // Half A: outputs [64L, 64L+32): inputs (prev, xs[0..30]); lane 0 has no
    //         prev step (output 0 is s0 itself): 31 steps, aA = beta^31.
    // Half B: outputs [64L+32, 64L+64): inputs xs[31..62]; 32 steps, aB = beta^32.
    float zA = (lane > 0) ? fmaf(alpha, prev * prev, omega) : 0.0f;
    float zB = 0.0f;
#pragma unroll
    for (int k = 0; k < 31; ++k) {
        zA = STEP(zA, xs[k]);
        zB = STEP(zB, xs[k + 31]);
    }
    zB = STEP(zB, xs[62]);                       // 32nd step of half B
    float aA = (lane == 0) ? beta31 : beta32;
    float ib = fmaf(beta32, zA, zB);             // compose B∘A
    float ia = aA * beta32;                      // beta^63 (lane 0) or beta^64

    // ---- Wave-level reduction (sum, ssq) ----
#pragma unroll
    for (int d = 32; d > 0; d >>= 1) {
        s1 += __shfl_xor(s1, d);
        s2 += __shfl_xor(s2, d);
    }
    float s0 = (s2 - s1 * s1 * (1.0f / T_COLS)) * (1.0f / (T_COLS - 1));
    s0 = fmaxf(s0, 0.0f);

    // ---- Wave-level inclusive affine scan over (ia, ib) ----
#pragma unroll
    for (int d = 1; d < 64; d <<= 1) {
        float pa = __shfl_up(ia, d);
        float pb = __shfl_up(ib, d);
        if (lane >= d) { ib = fmaf(ia, pb, ib); ia = ia * pa; }
    }

    // Exclusive prefix -> entry state = sigma2[64*lane - 1] (s0 for lane 0).
    float pea = __shfl_up(ia, 1);
    float peb = __shfl_up(ib, 1);
    if (lane == 0) { pea = 1.0f; peb = 0.0f; }
    float eA = fmaf(pea, s0, peb);
    float eB = fmaf(aA, eA, zA);                 // sigma2[64*lane + 31]

    // ---- Recompute + sqrt + store, two independent halves (interleave) ----
    float4* orow4 = reinterpret_cast<float4*>(out + row * T_COLS) + lane * 16;

    // Half A: outputs 0..31 (float4 j = 0..7)
    {
        float z;
        float4 q;
        if (lane == 0) { z = eA; }                                    // out 0 = s0
        else           { z = fmaf(beta, eA, fmaf(alpha, prev * prev, omega)); }
        q.x = SQ(z);
        z = STEP(z, xs[0]); q.y = SQ(z);
        z = STEP(z, xs[1]); q.z = SQ(z);
        z = STEP(z, xs[2]); q.w = SQ(z);
        orow4[0] = q;
#pragma unroll
        for (int j = 1; j < 8; ++j) {
            z = STEP(z, xs[4 * j - 1]); q.x = SQ(z);
            z = STEP(z, xs[4 * j + 0]); q.y = SQ(z);
            z = STEP(z, xs[4 * j + 1]); q.z = SQ(z);
            z = STEP(z, xs[4 * j + 2]); q.w = SQ(z);
            orow4[j] = q;
        }
    }
    // Half B: outputs 32..63 (float4 j = 8..15), entry state eB
    {
        float z = eB;
        float4 q;
#pragma unroll
        for (int j = 8; j < 16; ++j) {
            z = STEP(z, xs[4 * j - 1]); q.x = SQ(z);
            z = STEP(z, xs[4 * j + 0]); q.y = SQ(z);
            z = STEP(z, xs[4 * j + 1]); q.z = SQ(z);
            z = STEP(z, xs[4 * j + 2]); q.w = SQ(z);
            orow4[j] = q;
        }
    }
}

extern "C" void kernel_launch(void* const* d_in, const int* in_sizes, int n_in,
                              void* d_out, int out_size, void* d_ws, size_t ws_size,
                              hipStream_t stream) {
    const float* x         = (const float*)d_in[0];
    const float* omega_log = (const float*)d_in[1];
    const float* alpha_log = (const float*)d_in[2];
    const float* beta_log  = (const float*)d_in[3];
    float* out = (float*)d_out;

    garch_fused<<<NBLOCKS, NTHREADS, 0, stream>>>(x, omega_log, alpha_log, beta_log, out);
}

// Round 6
// 128.228 us; speedup vs baseline: 1.0089x; 1.0089x over previous
//
#include <hip/hip_runtime.h>
#include <math.h>

#define B_ROWS 4096
#define T_COLS 4096
#define NTHREADS 256
#define WPB (NTHREADS / 64)       // 4 waves per block, one ROW per WAVE
#define NBLOCKS (B_ROWS / WPB)    // 1024 blocks = 4/CU = 16 waves/CU

// Force a (wave-uniform) float into an SGPR.
__device__ __forceinline__ float rfl(float v) {
    return __int_as_float(__builtin_amdgcn_readfirstlane(__float_as_int(v)));
}

#define STEP(z, xv) fmaf(beta, (z), fmaf(alpha, (xv) * (xv), omega))
#define SQ(z) __builtin_amdgcn_sqrtf(z)

// Pin 16 floats into VGPRs: loads can't sink past this point, and the values
// can't be rematerialized by re-loading from global (the asm "writes" them).
#define PIN16(A)                                                            \
    asm volatile("" : "+v"((A)[0]), "+v"((A)[1]), "+v"((A)[2]), "+v"((A)[3]),   \
                      "+v"((A)[4]), "+v"((A)[5]), "+v"((A)[6]), "+v"((A)[7]),   \
                      "+v"((A)[8]), "+v"((A)[9]), "+v"((A)[10]), "+v"((A)[11]), \
                      "+v"((A)[12]), "+v"((A)[13]), "+v"((A)[14]), "+v"((A)[15]))

__global__ __launch_bounds__(NTHREADS, 4) void garch_fused(
    const float* __restrict__ x,
    const float* __restrict__ p_omega_log,
    const float* __restrict__ p_alpha_log,
    const float* __restrict__ p_beta_log,
    float* __restrict__ out)
{
    const int lane = threadIdx.x & 63;
    const int wv   = threadIdx.x >> 6;
    const long row = (long)blockIdx.x * WPB + wv;

    // ---- Strided loads: lane owns elements [64*lane, 64*lane+64) of its row.
    // All 16 dwordx4 issued back-to-back; the PINs below keep the whole row
    // resident in VGPRs for the rest of the kernel (single fetch, full MLP).
    const float4* xr4 = reinterpret_cast<const float4*>(x + row * T_COLS) + lane * 16;
    float xs[64];
#pragma unroll
    for (int j = 0; j < 16; ++j)
        *reinterpret_cast<float4*>(&xs[4 * j]) = xr4[j];
    PIN16(&xs[0]);
    PIN16(&xs[16]);
    PIN16(&xs[32]);
    PIN16(&xs[48]);

    // ---- Uniform scalar parameter work -> SGPRs ----
    float ea_p  = expf(p_alpha_log[0]);
    float eb_p  = expf(p_beta_log[0]);
    float denom = 1.0f + ea_p + eb_p;
    float omega = rfl(expf(p_omega_log[0]));
    float alpha = rfl(ea_p / denom);
    float beta  = rfl(eb_p / denom);
    float beta2  = beta * beta;
    float beta4  = beta2 * beta2;
    float beta8  = beta4 * beta4;
    float beta16 = beta8 * beta8;
    float beta32 = beta16 * beta16;
    float beta31 = beta16 * beta8 * beta4 * beta2 * beta;

    // ---- Per-lane sum/ssq over 64 elements (4 accumulators for ILP) ----
    float a0 = 0, a1 = 0, a2 = 0, a3 = 0, q0 = 0, q1 = 0, q2 = 0, q3 = 0;
#pragma unroll
    for (int k = 0; k < 64; k += 4) {
        a0 += xs[k + 0]; q0 = fmaf(xs[k + 0], xs[k + 0], q0);
        a1 += xs[k + 1]; q1 = fmaf(xs[k + 1], xs[k + 1], q1);
        a2 += xs[k + 2]; q2 = fmaf(xs[k + 2], xs[k + 2], q2);
        a3 += xs[k + 3]; q3 = fmaf(xs[k + 3], xs[k + 3], q3);
    }
    float s1 = (a0 + a1) + (a2 + a3);
    float s2 = (q0 + q1) + (q2 + q3);

    // prev = x[64*lane - 1]: lane-1's last element (unused by lane 0).
    float prev = __shfl_up(xs[63], 1);

    // ---- Zero-init affine map of this lane's 64-step segment, two independent
    // 32-step halves (2x ILP on the serial fma chain).
    // Half A: outputs [64L, 64L+32): inputs (prev, xs[0..30]); lane 0: 31 steps.
    // Half B: outputs [64L+32, 64L+64): inputs xs[31..62]; 32 steps.
    float zA = (lane > 0) ? fmaf(alpha, prev * prev, omega) : 0.0f;
    float zB = 0.0f;
#pragma unroll
    for (int k = 0; k < 31; ++k) {
        zA = STEP(zA, xs[k]);
        zB = STEP(zB, xs[k + 31]);
    }
    zB = STEP(zB, xs[62]);                       // 32nd step of half B
    float aA = (lane == 0) ? beta31 : beta32;
    float ib = fmaf(beta32, zA, zB);             // compose B after A
    float ia = aA * beta32;                      // beta^63 (lane 0) or beta^64

    // ---- Wave-level reduction (sum, ssq) ----
#pragma unroll
    for (int d = 32; d > 0; d >>= 1) {
        s1 += __shfl_xor(s1, d);
        s2 += __shfl_xor(s2, d);
    }
    float s0 = (s2 - s1 * s1 * (1.0f / T_COLS)) * (1.0f / (T_COLS - 1));
    s0 = fmaxf(s0, 0.0f);

    // ---- Wave-level inclusive affine scan over (ia, ib) ----
#pragma unroll
    for (int d = 1; d < 64; d <<= 1) {
        float pa = __shfl_up(ia, d);
        float pb = __shfl_up(ib, d);
        if (lane >= d) { ib = fmaf(ia, pb, ib); ia = ia * pa; }
    }

    // Exclusive prefix -> entry state = sigma2[64*lane - 1] (s0 for lane 0).
    float pea = __shfl_up(ia, 1);
    float peb = __shfl_up(ib, 1);
    if (lane == 0) { pea = 1.0f; peb = 0.0f; }
    float eA = fmaf(pea, s0, peb);
    float eB = fmaf(aA, eA, zA);                 // sigma2[64*lane + 31]

    // ---- Recompute + sqrt + store, two independent halves ----
    float4* orow4 = reinterpret_cast<float4*>(out + row * T_COLS) + lane * 16;

    // Half A: outputs 0..31 (float4 j = 0..7)
    {
        float z;
        float4 q;
        if (lane == 0) { z = eA; }                                    // out 0 = s0
        else           { z = fmaf(beta, eA, fmaf(alpha, prev * prev, omega)); }
        q.x = SQ(z);
        z = STEP(z, xs[0]); q.y = SQ(z);
        z = STEP(z, xs[1]); q.z = SQ(z);
        z = STEP(z, xs[2]); q.w = SQ(z);
        orow4[0] = q;
#pragma unroll
        for (int j = 1; j < 8; ++j) {
            z = STEP(z, xs[4 * j - 1]); q.x = SQ(z);
            z = STEP(z, xs[4 * j + 0]); q.y = SQ(z);
            z = STEP(z, xs[4 * j + 1]); q.z = SQ(z);
            z = STEP(z, xs[4 * j + 2]); q.w = SQ(z);
            orow4[j] = q;
        }
    }
    // Half B: outputs 32..63 (float4 j = 8..15), entry state eB
    {
        float z = eB;
        float4 q;
#pragma unroll
        for (int j = 8; j < 16; ++j) {
            z = STEP(z, xs[4 * j - 1]); q.x = SQ(z);
            z = STEP(z, xs[4 * j + 0]); q.y = SQ(z);
            z = STEP(z, xs[4 * j + 1]); q.z = SQ(z);
            z = STEP(z, xs[4 * j + 2]); q.w = SQ(z);
            orow4[j] = q;
        }
    }
}

extern "C" void kernel_launch(void* const* d_in, const int* in_sizes, int n_in,
                              void* d_out, int out_size, void* d_ws, size_t ws_size,
                              hipStream_t stream) {
    const float* x         = (const float*)d_in[0];
    const float* omega_log = (const float*)d_in[1];
    const float* alpha_log = (const float*)d_in[2];
    const float* beta_log  = (const float*)d_in[3];
    float* out = (float*)d_out;

    garch_fused<<<NBLOCKS, NTHREADS, 0, stream>>>(x, omega_log, alpha_log, beta_log, out);
}